// Round 7
// baseline (254.412 us; speedup 1.0000x reference)
//
#include <hip/hip_runtime.h>

#define B_DIM 8
#define N_DIM 2048
#define F_DIM 128

typedef __attribute__((ext_vector_type(8))) __bf16 bf16x8;
typedef __attribute__((ext_vector_type(4))) float f32x4;

__device__ __forceinline__ __bf16 f2bf(float f) {
  unsigned u = __builtin_bit_cast(unsigned, f);
  u += 0x7FFFu + ((u >> 16) & 1u);                 // round-to-nearest-even
  unsigned short s = (unsigned short)(u >> 16);
  return __builtin_bit_cast(__bf16, s);
}

// Kernel 1: supT[b][j][i] = bf16( sum_f x[b][i][f] * W[f][j] )   (transposed!)
// b = blockIdx&7 pins each batch to one XCD (round-robin dispatch) so supT[b]
// is produced in the same XCD L2 that gcn_adj (same pinning) reads it from.
__global__ __launch_bounds__(256) void gcn_xw(const float* __restrict__ x,
                                              const float* __restrict__ W,
                                              __bf16* __restrict__ supT) {
  __shared__ __bf16 WT[128 * 136];   // [j][f], stride 136 -> 2-way banks on read
  const int tid = threadIdx.x;
  const int lane = tid & 63;
  const int wave = tid >> 6;
  const int b = blockIdx.x & 7;
  const int i0 = (blockIdx.x >> 3) << 6;   // 64 nodes per WG

  {
    const int j = tid & 127;
    const int fh = (tid >> 7) << 6;          // 0 or 64
#pragma unroll
    for (int p = 0; p < 8; ++p) {
      const int f0 = fh + p * 8;
      bf16x8 v;
#pragma unroll
      for (int e = 0; e < 8; ++e)
        v[e] = f2bf(W[(size_t)(f0 + e) * 128 + j]);
      *reinterpret_cast<bf16x8*>(&WT[j * 136 + f0]) = v;
    }
  }
  __syncthreads();

  const int jt0 = wave << 1;           // each wave: 2 j-tiles x 4 i-tiles
  const int q8 = (lane >> 4) << 3;     // k offset of this quad
  const int c = lane & 15;
  f32x4 acc[2][4] = {};
  const float* xb = x + ((size_t)b * N_DIM + i0) * F_DIM;

  for (int k0 = 0; k0 < 128; k0 += 32) {
    const int kq = k0 + q8;
    bf16x8 af[2], bfr[4];
#pragma unroll
    for (int jt = 0; jt < 2; ++jt)
      af[jt] = *reinterpret_cast<const bf16x8*>(&WT[((jt0 + jt) * 16 + c) * 136 + kq]);
#pragma unroll
    for (int nt = 0; nt < 4; ++nt) {
      const float* xp = xb + (size_t)(nt * 16 + c) * F_DIM + kq;
      f32x4 x0 = *reinterpret_cast<const f32x4*>(xp);
      f32x4 x1 = *reinterpret_cast<const f32x4*>(xp + 4);
      bf16x8 v;
      v[0] = f2bf(x0.x); v[1] = f2bf(x0.y); v[2] = f2bf(x0.z); v[3] = f2bf(x0.w);
      v[4] = f2bf(x1.x); v[5] = f2bf(x1.y); v[6] = f2bf(x1.z); v[7] = f2bf(x1.w);
      bfr[nt] = v;
    }
#pragma unroll
    for (int jt = 0; jt < 2; ++jt)
#pragma unroll
      for (int nt = 0; nt < 4; ++nt)
        acc[jt][nt] = __builtin_amdgcn_mfma_f32_16x16x32_bf16(af[jt], bfr[nt],
                                                              acc[jt][nt], 0, 0, 0);
  }

  __bf16* sb = supT + (size_t)b * F_DIM * N_DIM;
  const int q = lane >> 4;
#pragma unroll
  for (int jt = 0; jt < 2; ++jt)
#pragma unroll
    for (int nt = 0; nt < 4; ++nt)
#pragma unroll
      for (int r = 0; r < 4; ++r) {
        int j = (jt0 + jt) * 16 + q * 4 + r;   // D row = quad*4 + reg
        int i = i0 + nt * 16 + c;              // D col = lane&15
        sb[(size_t)j * N_DIM + i] = f2bf(acc[jt][nt][r]);
      }
}

// Kernel 2: out[b][m][j] = sum_k adj[b][m][k] * supT[b][j][k] + bias[j]
// NO LDS, NO BARRIERS. Both operands load directly in MFMA fragment layout:
//   A-frag: adj[m0+mt*16+c][k+q8 .. +8]  = 32 B contiguous per lane; a wave's
//           64 lanes cover 16 rows x 128 B (coalesced).
//   B-frag: supT[nsub+nt*16+c][k+q8 .. ] = 16 B contiguous (k-major layout).
// Register double-buffer (A in f32, convert at use); waves free-run and
// de-phase so HBM always has loads in flight — no vmcnt(0)+barrier convoy
// (the R1-R6 structures measured ~70-79 us vs the ~21 us adj HBM floor).
// 32(M) x 128(N) per 256-thr block; wave = 32(M) x 32(N).
__global__ __launch_bounds__(256, 3) void gcn_adj(const float* __restrict__ adj,
                                                  const __bf16* __restrict__ supT,
                                                  const float* __restrict__ bias,
                                                  float* __restrict__ out) {
  const int tid = threadIdx.x;
  const int lane = tid & 63;
  const int wave = tid >> 6;
  const int b = blockIdx.x & 7;
  const int m0 = (blockIdx.x >> 3) << 5;   // 64 m-tiles per batch
  const int nsub = wave << 5;

  const int q8 = (lane >> 4) << 3;
  const int c = lane & 15;

  const float* a0 = adj + ((size_t)b * N_DIM + m0 + c) * N_DIM + q8;        // mt=0
  const float* a1 = a0 + (size_t)16 * N_DIM;                                 // mt=1
  const __bf16* sb = supT + (size_t)b * F_DIM * N_DIM;
  const __bf16* b0 = sb + (size_t)(nsub + c) * N_DIM + q8;                   // nt=0
  const __bf16* b1 = b0 + (size_t)16 * N_DIM;                                // nt=1

  f32x4 acur[8], anxt[8];    // [mt][k2][half]
  bf16x8 bcur[4], bnxt[4];   // [k2][nt]

  auto load_tile = [&](f32x4* a, bf16x8* bv, int k0) {
#pragma unroll
    for (int mt = 0; mt < 2; ++mt) {
      const float* ap = (mt ? a1 : a0) + k0;
#pragma unroll
      for (int k2 = 0; k2 < 2; ++k2) {
        a[mt * 4 + k2 * 2 + 0] = *reinterpret_cast<const f32x4*>(ap + k2 * 32);
        a[mt * 4 + k2 * 2 + 1] = *reinterpret_cast<const f32x4*>(ap + k2 * 32 + 4);
      }
    }
#pragma unroll
    for (int k2 = 0; k2 < 2; ++k2) {
      bv[k2 * 2 + 0] = *reinterpret_cast<const bf16x8*>(b0 + k0 + k2 * 32);
      bv[k2 * 2 + 1] = *reinterpret_cast<const bf16x8*>(b1 + k0 + k2 * 32);
    }
  };
  auto cvt = [&](const f32x4* a, int mt, int k2) {
    const f32x4 x0 = a[mt * 4 + k2 * 2 + 0];
    const f32x4 x1 = a[mt * 4 + k2 * 2 + 1];
    bf16x8 v;
    v[0] = f2bf(x0.x); v[1] = f2bf(x0.y); v[2] = f2bf(x0.z); v[3] = f2bf(x0.w);
    v[4] = f2bf(x1.x); v[5] = f2bf(x1.y); v[6] = f2bf(x1.z); v[7] = f2bf(x1.w);
    return v;
  };

  f32x4 acc[2][2] = {};

  load_tile(acur, bcur, 0);
  for (int it = 0; it < 32; ++it) {
    if (it < 31) load_tile(anxt, bnxt, (it + 1) * 64);   // next tile in flight
#pragma unroll
    for (int k2 = 0; k2 < 2; ++k2) {
      bf16x8 af0 = cvt(acur, 0, k2);
      bf16x8 af1 = cvt(acur, 1, k2);
      acc[0][0] = __builtin_amdgcn_mfma_f32_16x16x32_bf16(af0, bcur[k2 * 2 + 0], acc[0][0], 0, 0, 0);
      acc[0][1] = __builtin_amdgcn_mfma_f32_16x16x32_bf16(af0, bcur[k2 * 2 + 1], acc[0][1], 0, 0, 0);
      acc[1][0] = __builtin_amdgcn_mfma_f32_16x16x32_bf16(af1, bcur[k2 * 2 + 0], acc[1][0], 0, 0, 0);
      acc[1][1] = __builtin_amdgcn_mfma_f32_16x16x32_bf16(af1, bcur[k2 * 2 + 1], acc[1][1], 0, 0, 0);
    }
#pragma unroll
    for (int p = 0; p < 8; ++p) acur[p] = anxt[p];
#pragma unroll
    for (int p = 0; p < 4; ++p) bcur[p] = bnxt[p];
  }

  const int q = lane >> 4;
  float bv[2];
#pragma unroll
  for (int nt = 0; nt < 2; ++nt) bv[nt] = bias[nsub + nt * 16 + c];
#pragma unroll
  for (int mt = 0; mt < 2; ++mt)
#pragma unroll
    for (int nt = 0; nt < 2; ++nt)
#pragma unroll
      for (int r = 0; r < 4; ++r) {
        int m = m0 + mt * 16 + q * 4 + r;
        int j = nsub + nt * 16 + c;
        __builtin_nontemporal_store(acc[mt][nt][r] + bv[nt],
                                    &out[((size_t)b * N_DIM + m) * F_DIM + j]);
      }
}

extern "C" void kernel_launch(void* const* d_in, const int* in_sizes, int n_in,
                              void* d_out, int out_size, void* d_ws, size_t ws_size,
                              hipStream_t stream) {
  const float* x    = (const float*)d_in[0];
  const float* adj  = (const float*)d_in[1];
  const float* W    = (const float*)d_in[2];
  const float* bias = (const float*)d_in[3];
  float* out = (float*)d_out;
  __bf16* supT = (__bf16*)d_ws;   // 8*128*2048*2 = 4 MB scratch

  gcn_xw<<<B_DIM * 32, 256, 0, stream>>>(x, W, supT);
  gcn_adj<<<B_DIM * 64, 256, 0, stream>>>(adj, supT, bias, out);
}